// Round 1
// baseline (201.196 us; speedup 1.0000x reference)
//
#include <hip/hip_runtime.h>
#include <hip/hip_bf16.h>
#include <math.h>

#define F 8
#define C 4096
#define NPAIR 36            // F*(F+1)/2 pairs with i<=j
#define EPSF 1e-8f
#define NBLK 1024           // kernel-1 grid: 4 rows p per block (1 per wave)
#define QTILE 2048          // q-tile size; 8 factors * 2048 * 4B = 64 KB LDS

// ws layout (floats):
//   Gpart : [NPAIR][NBLK]   per-block partial sums of G_ij
//   srow  : [F][C]          row sums s_f[p]

__device__ __forceinline__ float wave_reduce(float v) {
    #pragma unroll
    for (int off = 32; off > 0; off >>= 1) v += __shfl_down(v, off, 64);
    return v;
}

__global__ __launch_bounds__(256) void pair_kernel(const float* __restrict__ x,
                                                   float* __restrict__ Gpart,
                                                   float* __restrict__ srow) {
    __shared__ __align__(16) float xs[F * QTILE];   // 64 KB
    const int tid  = threadIdx.x;
    const int lane = tid & 63;
    const int wave = tid >> 6;
    const int p    = blockIdx.x * 4 + wave;         // one row per wave

    float xp[F];
    #pragma unroll
    for (int f = 0; f < F; ++f) xp[f] = x[f * C + p];

    float g[NPAIR];
    #pragma unroll
    for (int k = 0; k < NPAIR; ++k) g[k] = 0.0f;
    float rs[F];
    #pragma unroll
    for (int f = 0; f < F; ++f) rs[f] = 0.0f;

    const float4* xg = (const float4*)x;

    for (int tile = 0; tile < C / QTILE; ++tile) {
        const int qb4 = (tile * QTILE) >> 2;        // float4 base of this tile
        __syncthreads();
        // stage 8 factors x 2048 floats = 4096 float4, 16 per thread, coalesced
        for (int i = tid; i < F * (QTILE / 4); i += 256) {
            const int f  = i >> 9;                  // / (QTILE/4)
            const int qq = i & (QTILE / 4 - 1);
            ((float4*)xs)[i] = xg[f * (C / 4) + qb4 + qq];
        }
        __syncthreads();

        for (int qt = 0; qt < QTILE / 4; qt += 64) {
            const int qi = qt + lane;               // float4 index within tile
            float4 v[F];
            #pragma unroll
            for (int f = 0; f < F; ++f) v[f] = ((const float4*)xs)[f * (QTILE / 4) + qi];

            float a0[F], a1[F], a2[F], a3[F];
            #pragma unroll
            for (int f = 0; f < F; ++f) {
                float d0 = xp[f] - v[f].x; a0[f] = sqrtf(d0 * d0 + EPSF);
                float d1 = xp[f] - v[f].y; a1[f] = sqrtf(d1 * d1 + EPSF);
                float d2 = xp[f] - v[f].z; a2[f] = sqrtf(d2 * d2 + EPSF);
                float d3 = xp[f] - v[f].w; a3[f] = sqrtf(d3 * d3 + EPSF);
                rs[f] += (a0[f] + a1[f]) + (a2[f] + a3[f]);
            }
            int k = 0;
            #pragma unroll
            for (int i = 0; i < F; ++i)
                #pragma unroll
                for (int j = i; j < F; ++j) {
                    g[k] += a0[i] * a0[j] + a1[i] * a1[j] + a2[i] * a2[j] + a3[i] * a3[j];
                    ++k;
                }
        }
    }

    // reduce within each wave (each wave owns one p)
    #pragma unroll
    for (int f = 0; f < F; ++f) rs[f] = wave_reduce(rs[f]);
    #pragma unroll
    for (int k = 0; k < NPAIR; ++k) g[k] = wave_reduce(g[k]);

    __syncthreads();                 // done reading xs; reuse for cross-wave reduce
    float* red = xs;                 // [4][NPAIR]
    if (lane == 0) {
        #pragma unroll
        for (int f = 0; f < F; ++f) srow[f * C + p] = rs[f];
        #pragma unroll
        for (int k = 0; k < NPAIR; ++k) red[wave * NPAIR + k] = g[k];
    }
    __syncthreads();
    if (tid < NPAIR) {
        float s = red[tid] + red[NPAIR + tid] + red[2 * NPAIR + tid] + red[3 * NPAIR + tid];
        Gpart[tid * NBLK + blockIdx.x] = s;
    }
}

__global__ __launch_bounds__(256) void finish_kernel(const float* __restrict__ Gpart,
                                                     const float* __restrict__ srow,
                                                     float* __restrict__ out) {
    const int tid  = threadIdx.x;
    const int lane = tid & 63;
    const int wave = tid >> 6;

    float D[NPAIR], G[NPAIR], T[F];
    #pragma unroll
    for (int k = 0; k < NPAIR; ++k) { D[k] = 0.0f; G[k] = 0.0f; }
    #pragma unroll
    for (int f = 0; f < F; ++f) T[f] = 0.0f;

    // 36 dot products <s_i, s_j> and 8 totals
    for (int p = tid; p < C; p += 256) {
        float sv[F];
        #pragma unroll
        for (int f = 0; f < F; ++f) { sv[f] = srow[f * C + p]; T[f] += sv[f]; }
        int k = 0;
        #pragma unroll
        for (int i = 0; i < F; ++i)
            #pragma unroll
            for (int j = i; j < F; ++j) { D[k] += sv[i] * sv[j]; ++k; }
    }
    // reduce the 1024 per-block G partials
    #pragma unroll
    for (int k = 0; k < NPAIR; ++k)
        for (int b = tid; b < NBLK; b += 256) G[k] += Gpart[k * NBLK + b];

    // wave reduce, then cross-wave via LDS
    #pragma unroll
    for (int k = 0; k < NPAIR; ++k) { G[k] = wave_reduce(G[k]); D[k] = wave_reduce(D[k]); }
    #pragma unroll
    for (int f = 0; f < F; ++f) T[f] = wave_reduce(T[f]);

    __shared__ float red[4][2 * NPAIR + F];
    if (lane == 0) {
        #pragma unroll
        for (int k = 0; k < NPAIR; ++k) { red[wave][k] = G[k]; red[wave][NPAIR + k] = D[k]; }
        #pragma unroll
        for (int f = 0; f < F; ++f) red[wave][2 * NPAIR + f] = T[f];
    }
    __syncthreads();
    if (tid == 0) {
        float Gt[NPAIR], Dt[NPAIR], Tt[F];
        for (int k = 0; k < NPAIR; ++k) {
            Gt[k] = red[0][k] + red[1][k] + red[2][k] + red[3][k];
            Dt[k] = red[0][NPAIR + k] + red[1][NPAIR + k] + red[2][NPAIR + k] + red[3][NPAIR + k];
        }
        for (int f = 0; f < F; ++f)
            Tt[f] = red[0][2 * NPAIR + f] + red[1][2 * NPAIR + f] +
                    red[2][2 * NPAIR + f] + red[3][2 * NPAIR + f];

        const float invC  = 1.0f / (float)C;        // 2^-12, exact
        const float invC2 = invC * invC;            // 2^-24, exact
        float dcov[NPAIR], diag[F];
        int k = 0;
        for (int i = 0; i < F; ++i)
            for (int j = i; j < F; ++j) {
                // S_ij = G/C^2 - 2<s_i,s_j>/C^3 + T_i T_j / C^4
                float S = Gt[k] * invC2 - 2.0f * Dt[k] * invC2 * invC +
                          (Tt[i] * invC2) * (Tt[j] * invC2);
                float dc = sqrtf(fmaxf(S, 0.0f) + EPSF);
                dcov[k] = dc;
                if (i == j) diag[i] = dc;
                ++k;
            }
        float cor = 0.0f;
        k = 0;
        for (int i = 0; i < F; ++i)
            for (int j = i; j < F; ++j) {
                if (j > i) cor += dcov[k] / sqrtf(diag[i] * diag[j] + EPSF);
                ++k;
            }
        out[0] = cor;
    }
}

extern "C" void kernel_launch(void* const* d_in, const int* in_sizes, int n_in,
                              void* d_out, int out_size, void* d_ws, size_t ws_size,
                              hipStream_t stream) {
    const float* x = (const float*)d_in[0];
    float* Gpart = (float*)d_ws;                 // 36 * 1024 floats
    float* srow  = Gpart + NPAIR * NBLK;         // 8 * 4096 floats
    float* out   = (float*)d_out;

    hipLaunchKernelGGL(pair_kernel,   dim3(NBLK), dim3(256), 0, stream, x, Gpart, srow);
    hipLaunchKernelGGL(finish_kernel, dim3(1),    dim3(256), 0, stream, Gpart, srow, out);
}

// Round 2
// 117.623 us; speedup vs baseline: 1.7105x; 1.7105x over previous
//
#include <hip/hip_runtime.h>
#include <hip/hip_bf16.h>
#include <math.h>

#define F 8
#define C 4096
#define NPAIR 36            // F*(F+1)/2 pairs with i<=j
#define EPSF 1e-8f
#define NBLK 1024           // kernel-1 grid: 4 rows p per block (1 per wave)
#define QTILE 1024          // q-tile size; 8 factors * 1024 * 4B = 32 KB LDS

// ws layout (floats):
//   Gpart : [NPAIR][NBLK]   per-block partial sums of G_ij
//   srow  : [F][C]          row sums s_f[p]

__device__ __forceinline__ float wave_reduce(float v) {
    #pragma unroll
    for (int off = 32; off > 0; off >>= 1) v += __shfl_down(v, off, 64);
    return v;
}

// raw v_sqrt_f32: 1 inst, ~1 ULP. Inputs are d*d+1e-8 in [1e-8, ~400] -> no
// denormal fixup needed (the ocml sqrtf expansion was ~15 VALU insts and was
// the dominant cost in R1).
__device__ __forceinline__ float fast_sqrt(float v) {
    return __builtin_amdgcn_sqrtf(v);
}

__global__ __launch_bounds__(256) void pair_kernel(const float* __restrict__ x,
                                                   float* __restrict__ Gpart,
                                                   float* __restrict__ srow) {
    __shared__ __align__(16) float xs[F * QTILE];   // 32 KB
    const int tid  = threadIdx.x;
    const int lane = tid & 63;
    const int wave = tid >> 6;
    const int p    = blockIdx.x * 4 + wave;         // one row per wave

    float xp[F];
    #pragma unroll
    for (int f = 0; f < F; ++f) xp[f] = x[f * C + p];

    float g[NPAIR];
    #pragma unroll
    for (int k = 0; k < NPAIR; ++k) g[k] = 0.0f;
    float rs[F];
    #pragma unroll
    for (int f = 0; f < F; ++f) rs[f] = 0.0f;

    const float4* xg = (const float4*)x;

    for (int tile = 0; tile < C / QTILE; ++tile) {
        const int qb4 = (tile * QTILE) >> 2;        // float4 base of this tile
        __syncthreads();
        // stage 8 factors x 1024 floats = 2048 float4, 8 per thread, coalesced
        for (int i = tid; i < F * (QTILE / 4); i += 256) {
            const int f  = i >> 8;                  // / (QTILE/4)
            const int qq = i & (QTILE / 4 - 1);
            ((float4*)xs)[i] = xg[f * (C / 4) + qb4 + qq];
        }
        __syncthreads();

        for (int qt = 0; qt < QTILE / 4; qt += 64) {
            const int qi = qt + lane;               // float4 index within tile
            float4 v[F];
            #pragma unroll
            for (int f = 0; f < F; ++f) v[f] = ((const float4*)xs)[f * (QTILE / 4) + qi];

            float a0[F], a1[F], a2[F], a3[F];
            #pragma unroll
            for (int f = 0; f < F; ++f) {
                float d0 = xp[f] - v[f].x; a0[f] = fast_sqrt(d0 * d0 + EPSF);
                float d1 = xp[f] - v[f].y; a1[f] = fast_sqrt(d1 * d1 + EPSF);
                float d2 = xp[f] - v[f].z; a2[f] = fast_sqrt(d2 * d2 + EPSF);
                float d3 = xp[f] - v[f].w; a3[f] = fast_sqrt(d3 * d3 + EPSF);
                rs[f] += (a0[f] + a1[f]) + (a2[f] + a3[f]);
            }
            int k = 0;
            #pragma unroll
            for (int i = 0; i < F; ++i)
                #pragma unroll
                for (int j = i; j < F; ++j) {
                    g[k] += a0[i] * a0[j] + a1[i] * a1[j] + a2[i] * a2[j] + a3[i] * a3[j];
                    ++k;
                }
        }
    }

    // reduce within each wave (each wave owns one p)
    #pragma unroll
    for (int f = 0; f < F; ++f) rs[f] = wave_reduce(rs[f]);
    #pragma unroll
    for (int k = 0; k < NPAIR; ++k) g[k] = wave_reduce(g[k]);

    __syncthreads();                 // done reading xs; reuse for cross-wave reduce
    float* red = xs;                 // [4][NPAIR]
    if (lane == 0) {
        #pragma unroll
        for (int f = 0; f < F; ++f) srow[f * C + p] = rs[f];
        #pragma unroll
        for (int k = 0; k < NPAIR; ++k) red[wave * NPAIR + k] = g[k];
    }
    __syncthreads();
    if (tid < NPAIR) {
        float s = red[tid] + red[NPAIR + tid] + red[2 * NPAIR + tid] + red[3 * NPAIR + tid];
        Gpart[tid * NBLK + blockIdx.x] = s;
    }
}

// 1024 threads = 16 waves. Phase A: 36 <s_i,s_j> dots + 8 totals (p strided by
// 1024). Phase B: each wave reduces Gpart rows k = wave, wave+16, wave+32.
// Cross-wave sums parallelized over first 44 threads; scalar epilogue on tid 0.
__global__ __launch_bounds__(1024) void finish_kernel(const float* __restrict__ Gpart,
                                                      const float* __restrict__ srow,
                                                      float* __restrict__ out) {
    const int tid  = threadIdx.x;
    const int lane = tid & 63;
    const int wave = tid >> 6;      // 0..15

    __shared__ float redD[16][NPAIR];
    __shared__ float redT[16][F];
    __shared__ float Gs[NPAIR];
    __shared__ float Dt[NPAIR];
    __shared__ float Tt[F];

    float D[NPAIR], T[F];
    #pragma unroll
    for (int k = 0; k < NPAIR; ++k) D[k] = 0.0f;
    #pragma unroll
    for (int f = 0; f < F; ++f) T[f] = 0.0f;

    #pragma unroll
    for (int it = 0; it < C / 1024; ++it) {         // 4 iters
        const int p = it * 1024 + tid;
        float sv[F];
        #pragma unroll
        for (int f = 0; f < F; ++f) { sv[f] = srow[f * C + p]; T[f] += sv[f]; }
        int k = 0;
        #pragma unroll
        for (int i = 0; i < F; ++i)
            #pragma unroll
            for (int j = i; j < F; ++j) { D[k] += sv[i] * sv[j]; ++k; }
    }
    #pragma unroll
    for (int k = 0; k < NPAIR; ++k) D[k] = wave_reduce(D[k]);
    #pragma unroll
    for (int f = 0; f < F; ++f) T[f] = wave_reduce(T[f]);
    if (lane == 0) {
        #pragma unroll
        for (int k = 0; k < NPAIR; ++k) redD[wave][k] = D[k];
        #pragma unroll
        for (int f = 0; f < F; ++f) redT[wave][f] = T[f];
    }

    // Phase B: G rows
    for (int k = wave; k < NPAIR; k += 16) {
        float s = 0.0f;
        #pragma unroll
        for (int it = 0; it < NBLK / 64; ++it) s += Gpart[k * NBLK + it * 64 + lane];
        s = wave_reduce(s);
        if (lane == 0) Gs[k] = s;
    }
    __syncthreads();

    if (tid < NPAIR) {
        float s = 0.0f;
        #pragma unroll
        for (int w = 0; w < 16; ++w) s += redD[w][tid];
        Dt[tid] = s;
    } else if (tid >= 64 && tid < 64 + F) {
        const int f = tid - 64;
        float s = 0.0f;
        #pragma unroll
        for (int w = 0; w < 16; ++w) s += redT[w][f];
        Tt[f] = s;
    }
    __syncthreads();

    if (tid == 0) {
        const float invC  = 1.0f / (float)C;        // 2^-12, exact
        const float invC2 = invC * invC;            // 2^-24, exact
        float dcov[NPAIR], diag[F];
        int k = 0;
        for (int i = 0; i < F; ++i)
            for (int j = i; j < F; ++j) {
                // S_ij = G/C^2 - 2<s_i,s_j>/C^3 + T_i T_j / C^4
                float S = Gs[k] * invC2 - 2.0f * Dt[k] * invC2 * invC +
                          (Tt[i] * invC2) * (Tt[j] * invC2);
                float dc = fast_sqrt(fmaxf(S, 0.0f) + EPSF);
                dcov[k] = dc;
                if (i == j) diag[i] = dc;
                ++k;
            }
        float cor = 0.0f;
        k = 0;
        for (int i = 0; i < F; ++i)
            for (int j = i; j < F; ++j) {
                if (j > i) cor += dcov[k] / fast_sqrt(diag[i] * diag[j] + EPSF);
                ++k;
            }
        out[0] = cor;
    }
}

extern "C" void kernel_launch(void* const* d_in, const int* in_sizes, int n_in,
                              void* d_out, int out_size, void* d_ws, size_t ws_size,
                              hipStream_t stream) {
    const float* x = (const float*)d_in[0];
    float* Gpart = (float*)d_ws;                 // 36 * 1024 floats
    float* srow  = Gpart + NPAIR * NBLK;         // 8 * 4096 floats
    float* out   = (float*)d_out;

    hipLaunchKernelGGL(pair_kernel,   dim3(NBLK), dim3(256), 0, stream, x, Gpart, srow);
    hipLaunchKernelGGL(finish_kernel, dim3(1),    dim3(1024), 0, stream, Gpart, srow, out);
}

// Round 3
// 104.120 us; speedup vs baseline: 1.9324x; 1.1297x over previous
//
#include <hip/hip_runtime.h>
#include <hip/hip_bf16.h>
#include <math.h>

#define F 8
#define C 4096
#define NPAIR 36            // F*(F+1)/2 pairs with i<=j
#define EPSF 1e-8f
#define NBLK 1024           // kernel-1 grid: 4 rows p per block (1 per wave)
#define QTILE 1024          // q-tile size; 8 factors * 1024 * 4B = 32 KB LDS

// Accumulator layout in ws (floats): 8 banks x 80 floats.
// Within a bank: G[36] | D[36] | T[8]. Banks spread atomic contention
// (blockIdx & 7); finish_kernel sums the 8 banks.
#define ACC_G 0
#define ACC_D 36
#define ACC_T 72
#define ACC_N 80
#define NBANK 8

__device__ __forceinline__ float wave_reduce(float v) {
    #pragma unroll
    for (int off = 32; off > 0; off >>= 1) v += __shfl_down(v, off, 64);
    return v;
}

// raw v_sqrt_f32 (epilogue only; main loop uses |d| since sqrt(d^2+1e-8)=|d|
// to within 1e-4 absolute, and only at d==0).
__device__ __forceinline__ float fast_sqrt(float v) {
    return __builtin_amdgcn_sqrtf(v);
}

__global__ __launch_bounds__(256) void zero_kernel(float* __restrict__ acc) {
    const int tid = threadIdx.x;
    if (tid < ACC_N * NBANK) acc[tid] = 0.0f;
}

__global__ __launch_bounds__(256) void pair_kernel(const float* __restrict__ x,
                                                   float* __restrict__ acc) {
    __shared__ __align__(16) float xs[F * QTILE];   // 32 KB; reused for reduce
    const int tid  = threadIdx.x;
    const int lane = tid & 63;
    const int wave = tid >> 6;
    const int p    = blockIdx.x * 4 + wave;         // one row per wave

    float xp[F];
    #pragma unroll
    for (int f = 0; f < F; ++f) xp[f] = x[f * C + p];

    float g[NPAIR];
    #pragma unroll
    for (int k = 0; k < NPAIR; ++k) g[k] = 0.0f;
    float rs[F];
    #pragma unroll
    for (int f = 0; f < F; ++f) rs[f] = 0.0f;

    const float4* xg = (const float4*)x;

    for (int tile = 0; tile < C / QTILE; ++tile) {
        const int qb4 = (tile * QTILE) >> 2;        // float4 base of this tile
        __syncthreads();
        // stage 8 factors x 1024 floats = 2048 float4, 8 per thread, coalesced
        for (int i = tid; i < F * (QTILE / 4); i += 256) {
            const int f  = i >> 8;                  // / (QTILE/4)
            const int qq = i & (QTILE / 4 - 1);
            ((float4*)xs)[i] = xg[f * (C / 4) + qb4 + qq];
        }
        __syncthreads();

        for (int qt = 0; qt < QTILE / 4; qt += 64) {
            const int qi = qt + lane;               // float4 index within tile
            float4 v[F];
            #pragma unroll
            for (int f = 0; f < F; ++f) v[f] = ((const float4*)xs)[f * (QTILE / 4) + qi];

            float a0[F], a1[F], a2[F], a3[F];
            #pragma unroll
            for (int f = 0; f < F; ++f) {
                a0[f] = __builtin_fabsf(xp[f] - v[f].x);
                a1[f] = __builtin_fabsf(xp[f] - v[f].y);
                a2[f] = __builtin_fabsf(xp[f] - v[f].z);
                a3[f] = __builtin_fabsf(xp[f] - v[f].w);
                rs[f] += (a0[f] + a1[f]) + (a2[f] + a3[f]);
            }
            int k = 0;
            #pragma unroll
            for (int i = 0; i < F; ++i)
                #pragma unroll
                for (int j = i; j < F; ++j) {
                    g[k] += a0[i] * a0[j] + a1[i] * a1[j] + a2[i] * a2[j] + a3[i] * a3[j];
                    ++k;
                }
        }
    }

    // reduce within each wave (each wave owns one p)
    #pragma unroll
    for (int f = 0; f < F; ++f) rs[f] = wave_reduce(rs[f]);
    #pragma unroll
    for (int k = 0; k < NPAIR; ++k) g[k] = wave_reduce(g[k]);

    __syncthreads();                 // done reading xs; reuse for cross-wave reduce
    float* red = xs;                 // [4][ACC_N]
    if (lane == 0) {
        #pragma unroll
        for (int k = 0; k < NPAIR; ++k) red[wave * ACC_N + ACC_G + k] = g[k];
        // D_ij contribution of this row p: s_i[p] * s_j[p]
        int k = 0;
        #pragma unroll
        for (int i = 0; i < F; ++i)
            #pragma unroll
            for (int j = i; j < F; ++j) { red[wave * ACC_N + ACC_D + k] = rs[i] * rs[j]; ++k; }
        #pragma unroll
        for (int f = 0; f < F; ++f) red[wave * ACC_N + ACC_T + f] = rs[f];
    }
    __syncthreads();
    if (tid < ACC_N) {
        float s = red[tid] + red[ACC_N + tid] + red[2 * ACC_N + tid] + red[3 * ACC_N + tid];
        atomicAdd(acc + (blockIdx.x & (NBANK - 1)) * ACC_N + tid, s);
    }
}

__global__ __launch_bounds__(128) void finish_kernel(const float* __restrict__ acc,
                                                     float* __restrict__ out) {
    __shared__ float A[ACC_N];
    const int tid = threadIdx.x;
    if (tid < ACC_N) {
        float s = 0.0f;
        #pragma unroll
        for (int b = 0; b < NBANK; ++b) s += acc[b * ACC_N + tid];
        A[tid] = s;
    }
    __syncthreads();
    if (tid == 0) {
        const float invC  = 1.0f / (float)C;        // 2^-12, exact
        const float invC2 = invC * invC;            // 2^-24, exact
        float dcov[NPAIR], diag[F];
        int k = 0;
        for (int i = 0; i < F; ++i)
            for (int j = i; j < F; ++j) {
                // S_ij = G/C^2 - 2 D/C^3 + T_i T_j / C^4
                float S = A[ACC_G + k] * invC2 - 2.0f * A[ACC_D + k] * invC2 * invC +
                          (A[ACC_T + i] * invC2) * (A[ACC_T + j] * invC2);
                float dc = fast_sqrt(fmaxf(S, 0.0f) + EPSF);
                dcov[k] = dc;
                if (i == j) diag[i] = dc;
                ++k;
            }
        float cor = 0.0f;
        k = 0;
        for (int i = 0; i < F; ++i)
            for (int j = i; j < F; ++j) {
                if (j > i) cor += dcov[k] * __builtin_amdgcn_rcpf(
                                      fast_sqrt(diag[i] * diag[j] + EPSF));
                ++k;
            }
        out[0] = cor;
    }
}

extern "C" void kernel_launch(void* const* d_in, const int* in_sizes, int n_in,
                              void* d_out, int out_size, void* d_ws, size_t ws_size,
                              hipStream_t stream) {
    const float* x = (const float*)d_in[0];
    float* acc = (float*)d_ws;                   // 8 banks * 80 floats
    float* out = (float*)d_out;

    hipLaunchKernelGGL(zero_kernel,   dim3(1),    dim3(256), 0, stream, acc);
    hipLaunchKernelGGL(pair_kernel,   dim3(NBLK), dim3(256), 0, stream, x, acc);
    hipLaunchKernelGGL(finish_kernel, dim3(1),    dim3(128), 0, stream, acc, out);
}